// Round 1
// 158.045 us; speedup vs baseline: 1.0118x; 1.0118x over previous
//
#include <hip/hip_runtime.h>
#include <math.h>

#define B_    64
#define A_    5
#define C_    80
#define GY_   32
#define GX_   32
#define N_    50
#define CH_   85
#define PLANE_ 1024   // GY*GX
#define NBLK_ (B_ * A_ * 4)   // 1280 blocks x 256 threads: one thread per box

__device__ __forceinline__ float sigmoidf_(float x) {
    return 1.0f / (1.0f + __expf(-x));
}

__device__ __forceinline__ float waveReduceSum(float v) {
    #pragma unroll
    for (int m = 32; m >= 1; m >>= 1) v += __shfl_xor(v, m, 64);
    return v;
}

__device__ __forceinline__ float waveReduceMax(float v) {
    #pragma unroll
    for (int m = 32; m >= 1; m >>= 1) v = fmaxf(v, __shfl_xor(v, m, 64));
    return v;
}

// Fused kernel. Block (b, a, chunk): 256 threads = quarter of a 32x32 plane.
// Global channel loads are issued BEFORE phase 0 so their ~900-cycle HBM
// latency overlaps the gt prep. Phase 2 (per-owner softmax) is parallelized
// across the block's 4 waves: owner threads export their coord/obj scalar to
// LDS, then wave w services owners i % 4 == w (concurrent class-channel
// gathers, no per-iteration block-wide ballot).
__global__ __launch_bounds__(256) void yolo_fused(
        const float* __restrict__ pred, const float* __restrict__ gt,
        const float* __restrict__ anc, const int* __restrict__ seen,
        float* __restrict__ partial) {
    __shared__ float4 sgt[N_];    // gt boxes, xyxy
    __shared__ float  sga[N_];    // 0.375 * gt area (iou>0.6 <=> inter>0.375*(Ag+Ap))
    __shared__ float4 senc[N_];   // regression targets
    __shared__ int    sbb[N_];    // best-box flat index (a*1024 + gy*32 + gx)
    __shared__ int    scls[N_];   // class id
    __shared__ int    slist[N_];  // gts whose best box lives in THIS block
    __shared__ float  sterm[N_];  // owner-thread coord+obj partial per owner entry
    __shared__ int    scnt;

    int bid = blockIdx.x;
    int b = bid / 20; int r = bid - b * 20;
    int a = r >> 2; int chunk = r & 3;
    int tid = threadIdx.x;

    // Issue the 5 coalesced channel-plane loads up front (latency overlap).
    int spatial = chunk * 256 + tid;
    int gy = spatial >> 5, gx = spatial & 31;
    const float* pb = pred + (size_t)(b * A_ + a) * (CH_ * PLANE_);
    const float* p = pb + spatial;
    float tx = p[0], ty = p[PLANE_], tw = p[2 * PLANE_],
          th = p[3 * PLANE_], to = p[4 * PLANE_];
    int seen0 = seen[0];

    // Phase 0: per-gt preprocessing — entirely in wave 0 (tid<50).
    // Owner list built with ballot + prefix-popcount (no LDS atomic, no init).
    if (tid < N_) {
        const float* g = gt + (b * N_ + tid) * 7;
        float dx = g[0], dy = g[1], gxf = g[2], gyf = g[3], gw = g[4], gh = g[5];
        float best = -1.0f; int bp = 0;
        #pragma unroll
        for (int aa = 0; aa < A_; aa++) {
            float aw = anc[2 * aa], ah = anc[2 * aa + 1];
            float inter = fminf(gw, aw) * fminf(gh, ah);
            float iou = inter / (gw * gh + aw * ah - inter);
            if (iou > best) { best = iou; bp = aa; }   // first-max wins = jnp.argmax
        }
        int bb = bp * PLANE_ + (int)gyf * GX_ + (int)gxf;
        sbb[tid] = bb;
        float cx = dx + gxf * (1.0f / 32.0f);
        float cy = dy + gyf * (1.0f / 32.0f);
        sgt[tid]  = make_float4(cx - gw * 0.5f, cy - gh * 0.5f,
                                cx + gw * 0.5f, cy + gh * 0.5f);
        sga[tid]  = 0.375f * gw * gh;
        senc[tid] = make_float4(dx, dy, __logf(gw) - __logf(anc[2 * bp]),
                                        __logf(gh) - __logf(anc[2 * bp + 1]));
        scls[tid] = (int)g[6];
        // owner-list: gts whose best box falls in this block's (a, chunk) range
        bool ownHere = ((bb >> 10) == a) && (((bb & 1023) >> 8) == chunk);
        unsigned long long mask = __ballot(ownHere);   // lanes >=50 inactive -> 0
        if (ownHere) {
            int slot = __popcll(mask & ((1ULL << tid) - 1ULL));
            slist[slot] = tid;
        }
        if (tid == 0) scnt = (int)__popcll(mask);
    }
    __syncthreads();

    // Phase 1: per-box work, division-free overlap test.
    float sx = sigmoidf_(tx), sy = sigmoidf_(ty), so = sigmoidf_(to);
    float pcx = sx + (float)gx * (1.0f / 32.0f);
    float pcy = sy + (float)gy * (1.0f / 32.0f);
    float pw = anc[2 * a] * __expf(tw);
    float ph = anc[2 * a + 1] * __expf(th);
    float px1 = pcx - pw * 0.5f, py1 = pcy - ph * 0.5f;
    float px2 = pcx + pw * 0.5f, py2 = pcy + ph * 0.5f;
    float areap = pw * ph;
    float a375p = 0.375f * areap;

    bool anyHigh = false;
    #pragma unroll 10
    for (int n = 0; n < N_; n++) {
        float4 gb = sgt[n];
        float ix = fmaxf(fminf(gb.z, px2) - fmaxf(gb.x, px1), 0.0f);
        float iy = fmaxf(fminf(gb.w, py2) - fmaxf(gb.y, py1), 0.0f);
        // iou > 0.6  <=>  ix*iy - 0.375*areap > 0.375*areag
        anyHigh = anyHigh || (__builtin_fmaf(ix, iy, -a375p) > sga[n]);
    }

    // Phase 1b: owner threads export their coord+obj scalar for each owned
    // entry (avg ~2.5 entries/block; at most one owner thread per entry).
    int lane = tid & 63;
    int wave = tid >> 6;
    int myIdx = a * PLANE_ + spatial;
    bool isBest = false;
    int cnt = scnt;
    for (int i = 0; i < cnt; i++) {
        int n = slist[i];
        if (sbb[n] == myIdx) {
            isBest = true;
            float4 gb = sgt[n];
            float ix = fmaxf(fminf(gb.z, px2) - fmaxf(gb.x, px1), 0.0f);
            float iy = fmaxf(fminf(gb.w, py2) - fmaxf(gb.y, py1), 0.0f);
            float inter = ix * iy;
            float areag = (gb.z - gb.x) * (gb.w - gb.y);
            float iou_t = inter / (areag + areap - inter);
            float4 e = senc[n];
            float c0 = sx - e.x, c1 = sy - e.y, c2 = tw - e.z, c3 = th - e.w;
            float ot = so - iou_t;
            sterm[i] = c0 * c0 + c1 * c1 + c2 * c2 + c3 * c3
                     + 5.0f * ot * ot;                     // LAMBDA_OBJ=5
        }
    }
    __syncthreads();

    // Phase 2: wave-parallel over owner entries — wave w takes i = w, w+4, ...
    // All 64 lanes of the wave cooperate on the 80-class softmax at the
    // owner's cell; lane 0 folds in the exported coord/obj scalar.
    float acc = 0.0f;
    for (int i = wave; i < cnt; i += 4) {
        int n = slist[i];
        int sp = sbb[n] & 1023;
        float z1 = pb[(5 + lane) * PLANE_ + sp];
        float z2 = (lane < 16) ? pb[(69 + lane) * PLANE_ + sp] : -1e30f;
        float m = waveReduceMax(fmaxf(z1, z2));
        float e1 = __expf(z1 - m);
        float e2 = (lane < 16) ? __expf(z2 - m) : 0.0f;
        float S = waveReduceSum(e1 + e2);
        float inv = 1.0f / S;

        int cls = scls[n];
        float d1 = e1 * inv - ((lane == cls) ? 1.0f : 0.0f);
        float term = d1 * d1;
        if (lane < 16) {
            float d2 = e2 * inv - (((64 + lane) == cls) ? 1.0f : 0.0f);
            term += d2 * d2;
        }
        float clsSum = waveReduceSum(term);
        if (lane == 0) acc += clsSum + sterm[i];
    }

    // noobj + prior (posf: 1 if best box, else 2 if overlap>0.6, else 0)
    if (!isBest) {
        if (!anyHigh) acc += so * so;                      // LAMBDA_NOOBJ=1
        if (seen0 < 12800) {
            float d0 = sx - 0.015625f, d1 = sy - 0.015625f; // 0.5/32
            acc += 0.01f * (d0 * d0 + d1 * d1 + tw * tw + th * th); // LAMBDA_PRIOR
        }
    }

    // Block reduction -> one partial per block (no global atomics)
    acc = waveReduceSum(acc);
    __shared__ float part[4];
    if (lane == 0) part[wave] = acc;
    __syncthreads();
    if (tid == 0) partial[bid] = part[0] + part[1] + part[2] + part[3];
}

// Final reduction: 1280 partials -> scalar. One block of 320 threads, float4.
__global__ __launch_bounds__(320) void yolo_reduce(
        const float* __restrict__ partial, float* __restrict__ out) {
    int tid = threadIdx.x;
    float4 v4 = ((const float4*)partial)[tid];   // 320 * 4 = 1280
    float v = (v4.x + v4.y) + (v4.z + v4.w);
    v = waveReduceSum(v);
    __shared__ float part[5];
    if ((tid & 63) == 0) part[tid >> 6] = v;
    __syncthreads();
    if (tid == 0) out[0] = part[0] + part[1] + part[2] + part[3] + part[4];
}

extern "C" void kernel_launch(void* const* d_in, const int* in_sizes, int n_in,
                              void* d_out, int out_size, void* d_ws, size_t ws_size,
                              hipStream_t stream) {
    const float* pred = (const float*)d_in[0];
    const float* gt   = (const float*)d_in[1];
    const float* anc  = (const float*)d_in[2];
    const int*   seen = (const int*)d_in[3];
    float* out = (float*)d_out;
    float* partial = (float*)d_ws;   // 1280 floats; fully written before read

    yolo_fused<<<NBLK_, 256, 0, stream>>>(pred, gt, anc, seen, partial);
    yolo_reduce<<<1, 320, 0, stream>>>(partial, out);
}

// Round 2
// 156.412 us; speedup vs baseline: 1.0223x; 1.0104x over previous
//
#include <hip/hip_runtime.h>
#include <math.h>

#define B_    64
#define A_    5
#define C_    80
#define GY_   32
#define GX_   32
#define N_    50
#define CH_   85
#define PLANE_ 1024   // GY*GX
#define NBLK_ (B_ * A_ * 4)   // 1280 blocks x 256 threads: one thread per box

__device__ __forceinline__ float sigmoidf_(float x) {
    return 1.0f / (1.0f + __expf(-x));
}

__device__ __forceinline__ float waveReduceSum(float v) {
    #pragma unroll
    for (int m = 32; m >= 1; m >>= 1) v += __shfl_xor(v, m, 64);
    return v;
}

__device__ __forceinline__ float waveReduceMax(float v) {
    #pragma unroll
    for (int m = 32; m >= 1; m >>= 1) v = fmaxf(v, __shfl_xor(v, m, 64));
    return v;
}

// Fused kernel. Block (b, a, chunk): 256 threads = quarter of a 32x32 plane.
// Single block-wide barrier on the main path:
//  - the 5 channel-plane loads are issued before phase 0 (HBM latency overlap)
//  - the wave's first phase-2 class gather is issued right after the barrier,
//    so its ~900-cycle cold-miss latency hides under phase 1's IoU VALU loop
//  - the owner thread folds coord/obj into its own accumulator (no sterm LDS
//    round-trip, no second barrier); the servicing wave adds only clsSum.
__global__ __launch_bounds__(256) void yolo_fused(
        const float* __restrict__ pred, const float* __restrict__ gt,
        const float* __restrict__ anc, const int* __restrict__ seen,
        float* __restrict__ partial) {
    __shared__ float4 sgt[N_];    // gt boxes, xyxy
    __shared__ float  sga[N_];    // 0.375 * gt area (iou>0.6 <=> inter>0.375*(Ag+Ap))
    __shared__ float4 senc[N_];   // regression targets
    __shared__ int    sbb[N_];    // best-box flat index (a*1024 + gy*32 + gx)
    __shared__ int    scls[N_];   // class id
    __shared__ int    slist[N_];  // gts whose best box lives in THIS block
    __shared__ int    scnt;

    int bid = blockIdx.x;
    int b = bid / 20; int r = bid - b * 20;
    int a = r >> 2; int chunk = r & 3;
    int tid = threadIdx.x;

    // Issue the 5 coalesced channel-plane loads up front (latency overlap).
    int spatial = chunk * 256 + tid;
    int gy = spatial >> 5, gx = spatial & 31;
    const float* pb = pred + (size_t)(b * A_ + a) * (CH_ * PLANE_);
    const float* p = pb + spatial;
    float tx = p[0], ty = p[PLANE_], tw = p[2 * PLANE_],
          th = p[3 * PLANE_], to = p[4 * PLANE_];
    int seen0 = seen[0];

    // Phase 0: per-gt preprocessing — entirely in wave 0 (tid<50).
    // Owner list built with ballot + prefix-popcount (no LDS atomic, no init).
    if (tid < N_) {
        const float* g = gt + (b * N_ + tid) * 7;
        float dx = g[0], dy = g[1], gxf = g[2], gyf = g[3], gw = g[4], gh = g[5];
        float best = -1.0f; int bp = 0;
        #pragma unroll
        for (int aa = 0; aa < A_; aa++) {
            float aw = anc[2 * aa], ah = anc[2 * aa + 1];
            float inter = fminf(gw, aw) * fminf(gh, ah);
            float iou = inter / (gw * gh + aw * ah - inter);
            if (iou > best) { best = iou; bp = aa; }   // first-max wins = jnp.argmax
        }
        int bb = bp * PLANE_ + (int)gyf * GX_ + (int)gxf;
        sbb[tid] = bb;
        float cx = dx + gxf * (1.0f / 32.0f);
        float cy = dy + gyf * (1.0f / 32.0f);
        sgt[tid]  = make_float4(cx - gw * 0.5f, cy - gh * 0.5f,
                                cx + gw * 0.5f, cy + gh * 0.5f);
        sga[tid]  = 0.375f * gw * gh;
        senc[tid] = make_float4(dx, dy, __logf(gw) - __logf(anc[2 * bp]),
                                        __logf(gh) - __logf(anc[2 * bp + 1]));
        scls[tid] = (int)g[6];
        // owner-list: gts whose best box falls in this block's (a, chunk) range
        bool ownHere = ((bb >> 10) == a) && (((bb & 1023) >> 8) == chunk);
        unsigned long long mask = __ballot(ownHere);   // lanes >=50 inactive -> 0
        if (ownHere) {
            int slot = __popcll(mask & ((1ULL << tid) - 1ULL));
            slist[slot] = tid;
        }
        if (tid == 0) scnt = (int)__popcll(mask);
    }
    __syncthreads();

    int lane = tid & 63;
    int wave = tid >> 6;
    int cnt = scnt;

    // Early-issue the wave's first phase-2 class gather (avg 0.625 entries per
    // wave, so this covers almost all of them). Its cold-miss latency hides
    // under the phase-1 VALU loop below.
    float z1_0 = 0.0f, z2_0 = -1e30f;
    int n0 = 0;
    if (wave < cnt) {
        n0 = slist[wave];
        int sp0 = sbb[n0] & 1023;
        z1_0 = pb[(5 + lane) * PLANE_ + sp0];
        z2_0 = (lane < 16) ? pb[(69 + lane) * PLANE_ + sp0] : -1e30f;
    }

    // Phase 1: per-box work, division-free overlap test.
    float sx = sigmoidf_(tx), sy = sigmoidf_(ty), so = sigmoidf_(to);
    float pcx = sx + (float)gx * (1.0f / 32.0f);
    float pcy = sy + (float)gy * (1.0f / 32.0f);
    float pw = anc[2 * a] * __expf(tw);
    float ph = anc[2 * a + 1] * __expf(th);
    float px1 = pcx - pw * 0.5f, py1 = pcy - ph * 0.5f;
    float px2 = pcx + pw * 0.5f, py2 = pcy + ph * 0.5f;
    float areap = pw * ph;
    float a375p = 0.375f * areap;

    bool anyHigh = false;
    #pragma unroll 10
    for (int n = 0; n < N_; n++) {
        float4 gb = sgt[n];
        float ix = fmaxf(fminf(gb.z, px2) - fmaxf(gb.x, px1), 0.0f);
        float iy = fmaxf(fminf(gb.w, py2) - fmaxf(gb.y, py1), 0.0f);
        // iou > 0.6  <=>  ix*iy - 0.375*areap > 0.375*areag
        anyHigh = anyHigh || (__builtin_fmaf(ix, iy, -a375p) > sga[n]);
    }

    // Phase 1b: owner threads fold their coord+obj terms directly into their
    // own accumulator (block sum makes the association irrelevant) — no LDS
    // hand-off, no second barrier.
    int myIdx = a * PLANE_ + spatial;
    bool isBest = false;
    float acc = 0.0f;
    for (int i = 0; i < cnt; i++) {
        int n = slist[i];
        if (sbb[n] == myIdx) {
            isBest = true;
            float4 gb = sgt[n];
            float ix = fmaxf(fminf(gb.z, px2) - fmaxf(gb.x, px1), 0.0f);
            float iy = fmaxf(fminf(gb.w, py2) - fmaxf(gb.y, py1), 0.0f);
            float inter = ix * iy;
            float areag = (gb.z - gb.x) * (gb.w - gb.y);
            float iou_t = inter / (areag + areap - inter);
            float4 e = senc[n];
            float c0 = sx - e.x, c1 = sy - e.y, c2 = tw - e.z, c3 = th - e.w;
            float ot = so - iou_t;
            acc += c0 * c0 + c1 * c1 + c2 * c2 + c3 * c3
                 + 5.0f * ot * ot;                         // LAMBDA_OBJ=5
        }
    }

    // Phase 2: wave-parallel over owner entries — wave w takes i = w, w+4, ...
    // All 64 lanes cooperate on the 80-class softmax at the owner's cell.
    for (int i = wave; i < cnt; i += 4) {
        int n; float z1, z2;
        if (i == wave) {          // pre-issued above
            n = n0; z1 = z1_0; z2 = z2_0;
        } else {                  // rare (cnt > 4)
            n = slist[i];
            int sp = sbb[n] & 1023;
            z1 = pb[(5 + lane) * PLANE_ + sp];
            z2 = (lane < 16) ? pb[(69 + lane) * PLANE_ + sp] : -1e30f;
        }
        float m = waveReduceMax(fmaxf(z1, z2));
        float e1 = __expf(z1 - m);
        float e2 = (lane < 16) ? __expf(z2 - m) : 0.0f;
        float S = waveReduceSum(e1 + e2);
        float inv = 1.0f / S;

        int cls = scls[n];
        float d1 = e1 * inv - ((lane == cls) ? 1.0f : 0.0f);
        float term = d1 * d1;
        if (lane < 16) {
            float d2 = e2 * inv - (((64 + lane) == cls) ? 1.0f : 0.0f);
            term += d2 * d2;
        }
        float clsSum = waveReduceSum(term);
        if (lane == 0) acc += clsSum;
    }

    // noobj + prior (posf: 1 if best box, else 2 if overlap>0.6, else 0)
    if (!isBest) {
        if (!anyHigh) acc += so * so;                      // LAMBDA_NOOBJ=1
        if (seen0 < 12800) {
            float d0 = sx - 0.015625f, d1 = sy - 0.015625f; // 0.5/32
            acc += 0.01f * (d0 * d0 + d1 * d1 + tw * tw + th * th); // LAMBDA_PRIOR
        }
    }

    // Block reduction -> one partial per block (no global atomics)
    acc = waveReduceSum(acc);
    __shared__ float part[4];
    if (lane == 0) part[wave] = acc;
    __syncthreads();
    if (tid == 0) partial[bid] = part[0] + part[1] + part[2] + part[3];
}

// Final reduction: 1280 partials -> scalar. One block of 320 threads, float4.
__global__ __launch_bounds__(320) void yolo_reduce(
        const float* __restrict__ partial, float* __restrict__ out) {
    int tid = threadIdx.x;
    float4 v4 = ((const float4*)partial)[tid];   // 320 * 4 = 1280
    float v = (v4.x + v4.y) + (v4.z + v4.w);
    v = waveReduceSum(v);
    __shared__ float part[5];
    if ((tid & 63) == 0) part[tid >> 6] = v;
    __syncthreads();
    if (tid == 0) out[0] = part[0] + part[1] + part[2] + part[3] + part[4];
}

extern "C" void kernel_launch(void* const* d_in, const int* in_sizes, int n_in,
                              void* d_out, int out_size, void* d_ws, size_t ws_size,
                              hipStream_t stream) {
    const float* pred = (const float*)d_in[0];
    const float* gt   = (const float*)d_in[1];
    const float* anc  = (const float*)d_in[2];
    const int*   seen = (const int*)d_in[3];
    float* out = (float*)d_out;
    float* partial = (float*)d_ws;   // 1280 floats; fully written before read

    yolo_fused<<<NBLK_, 256, 0, stream>>>(pred, gt, anc, seen, partial);
    yolo_reduce<<<1, 320, 0, stream>>>(partial, out);
}